// Round 2
// baseline (4355.997 us; speedup 1.0000x reference)
//
#include <hip/hip_runtime.h>
#include <hip/hip_bf16.h>

#define B_    16
#define C_    128
#define H_    112
#define W_    112
#define OUTC_ 256
#define TWOC_ 256
#define HW_   (H_ * W_)           // 12544
#define CHW_  ((size_t)C_ * HW_)  // 1605632

typedef __hip_bfloat16 bf16;

__device__ __forceinline__ float b2f(bf16 v) { return __bfloat162float(v); }
__device__ __forceinline__ bf16  f2b(float v) { return __float2bfloat16(v); }

__device__ __forceinline__ float rd(const float* p) { return *p; }
__device__ __forceinline__ float rd(const bf16* p)  { return b2f(*p); }
__device__ __forceinline__ void  wr(float* p, float v) { *p = v; }
__device__ __forceinline__ void  wr(bf16* p,  float v) { *p = f2b(v); }

__device__ __forceinline__ float fast_tanh(float v) {
    float e = __expf(2.f * v);
    return 1.f - 2.f / (e + 1.f);
}

// ---------------------------------------------------------------------------
// Probe: detect input dtype. bf16 N(0,1) data has no element with exp>=135
// (|v|>=256); fp32 data read as bf16 halves has ~47% of low-halves there.
// flag=1 -> inputs are fp32; flag=0 -> inputs are bf16.
// ---------------------------------------------------------------------------
__global__ __launch_bounds__(256) void k_probe(const unsigned short* __restrict__ x,
                                               int* __restrict__ flag) {
    __shared__ int cnt[256];
    int tid = threadIdx.x;
    int c = 0;
#pragma unroll
    for (int i = 0; i < 8; ++i) {
        unsigned short u = x[tid * 8 + i];
        int e = (u >> 7) & 0xFF;
        if (e >= 135 && e != 0) c++;
    }
    cnt[tid] = c;
    __syncthreads();
    if (tid == 0) {
        int s = 0;
        for (int i = 0; i < 256; ++i) s += cnt[i];
        *flag = (s > 64) ? 1 : 0;
    }
}

// ---------------------------------------------------------------------------
// Kernel 1: offset = tanh(conv3x3(x, offset_w) + offset_b), fp32 out
// ---------------------------------------------------------------------------
#define OCT 4
template <typename TI>
__device__ void offset_body(const TI* __restrict__ x, const TI* __restrict__ ow,
                            const TI* __restrict__ ob, float* __restrict__ off,
                            float* wl) {
    const int tid = threadIdx.x;
    const int ocb = blockIdx.z * OCT;
    for (int i = tid; i < OCT * C_ * 9; i += 256) {
        int j = i / (C_ * 9);
        int rem = i - j * (C_ * 9);   // = c*9 + k
        int c = rem / 9;
        int k = rem - c * 9;
        wl[c * (OCT * 9) + j * 9 + k] = rd(ow + (size_t)(ocb + j) * (C_ * 9) + rem);
    }
    __syncthreads();

    const int wcol = tid & 127;
    const int r = tid >> 7;
    const int h = blockIdx.x * 2 + r;
    const int b = blockIdx.y;
    if (wcol >= W_) return;

    const TI* xb = x + (size_t)b * CHW_;
    float acc0 = 0.f, acc1 = 0.f, acc2 = 0.f, acc3 = 0.f;

    for (int c = 0; c < C_; ++c) {
        const TI* xc = xb + (size_t)c * HW_;
        const float* wc = wl + c * (OCT * 9);
        float xv[9];
#pragma unroll
        for (int kh = 0; kh < 3; ++kh) {
            int hh = h + kh - 1;
            bool hv = (hh >= 0) && (hh < H_);
            const TI* xr = xc + hh * W_;
#pragma unroll
            for (int kw = 0; kw < 3; ++kw) {
                int ww = wcol + kw - 1;
                bool v = hv && (ww >= 0) && (ww < W_);
                xv[kh * 3 + kw] = v ? rd(xr + ww) : 0.f;
            }
        }
#pragma unroll
        for (int k = 0; k < 9; ++k) {
            acc0 += xv[k] * wc[k];
            acc1 += xv[k] * wc[9 + k];
            acc2 += xv[k] * wc[18 + k];
            acc3 += xv[k] * wc[27 + k];
        }
    }

    size_t obase = (size_t)b * TWOC_ * HW_ + (size_t)h * W_ + wcol;
    off[obase + (size_t)(ocb + 0) * HW_] = fast_tanh(acc0 + rd(ob + ocb + 0));
    off[obase + (size_t)(ocb + 1) * HW_] = fast_tanh(acc1 + rd(ob + ocb + 1));
    off[obase + (size_t)(ocb + 2) * HW_] = fast_tanh(acc2 + rd(ob + ocb + 2));
    off[obase + (size_t)(ocb + 3) * HW_] = fast_tanh(acc3 + rd(ob + ocb + 3));
}

__global__ __launch_bounds__(256) void k_offset_conv(
    const void* x, const void* ow, const void* ob, float* off, const int* flag) {
    __shared__ float wl[C_ * OCT * 9];  // 18432 B
    if (*flag)
        offset_body<float>((const float*)x, (const float*)ow, (const float*)ob, off, wl);
    else
        offset_body<bf16>((const bf16*)x, (const bf16*)ow, (const bf16*)ob, off, wl);
}

// ---------------------------------------------------------------------------
// Kernel 2: depthwise 3x3. grid (49, C, B).
// ---------------------------------------------------------------------------
template <typename TI>
__device__ void dw_body(const TI* __restrict__ x, const TI* __restrict__ dw,
                        bf16* __restrict__ out) {
    int hw = blockIdx.x * 256 + threadIdx.x;  // 49*256 == 12544
    int c = blockIdx.y, b = blockIdx.z;
    int h = hw / W_, w = hw - h * W_;
    float wv[9];
#pragma unroll
    for (int k = 0; k < 9; ++k) wv[k] = rd(dw + c * 9 + k);
    const TI* xc = x + (size_t)b * CHW_ + (size_t)c * HW_;
    float acc = 0.f;
#pragma unroll
    for (int kh = 0; kh < 3; ++kh) {
        int hh = h + kh - 1;
        bool hv = (hh >= 0) && (hh < H_);
#pragma unroll
        for (int kw = 0; kw < 3; ++kw) {
            int ww = w + kw - 1;
            bool v = hv && (ww >= 0) && (ww < W_);
            acc += (v ? rd(xc + hh * W_ + ww) : 0.f) * wv[kh * 3 + kw];
        }
    }
    out[(size_t)(b * C_ + c) * HW_ + hw] = f2b(acc);
}

__global__ __launch_bounds__(256) void k_dw(const void* x, const void* dw,
                                            bf16* out, const int* flag) {
    if (*flag) dw_body<float>((const float*)x, (const float*)dw, out);
    else       dw_body<bf16>((const bf16*)x, (const bf16*)dw, out);
}

// ---------------------------------------------------------------------------
// Kernel 3: grid sample (no input-dtype dependence). grid (49, C, B).
// Channel c uses offset channels (2c, 2c+1); BOTH coordinate bases are
// gX[w] for c<64 and gY[h] for c>=64 (ref reshape quirk).
// ---------------------------------------------------------------------------
__global__ __launch_bounds__(256) void k_sample(
    const float* __restrict__ off, const bf16* __restrict__ dwout,
    bf16* __restrict__ samp) {
    int hw = blockIdx.x * 256 + threadIdx.x;
    int c = blockIdx.y, b = blockIdx.z;
    int h = hw / W_, w = hw - h * W_;

    float gbase = (c < 64) ? (-1.f + 2.f * (float)w / 111.f)
                           : (-1.f + 2.f * (float)h / 111.f);
    const float* offb = off + (size_t)b * TWOC_ * HW_;
    float ox = offb[(size_t)(2 * c) * HW_ + hw];
    float oy = offb[(size_t)(2 * c + 1) * HW_ + hw];
    float gx = fminf(fmaxf(gbase + ox, -1.f), 1.f);
    float gy = fminf(fmaxf(gbase + oy, -1.f), 1.f);
    float ix = (gx + 1.f) * 56.f - 0.5f;
    float iy = (gy + 1.f) * 56.f - 0.5f;
    float x0f = floorf(ix), y0f = floorf(iy);
    float wx = ix - x0f, wy = iy - y0f;
    int x0 = (int)x0f, y0 = (int)y0f;

    const bf16* p = dwout + (size_t)(b * C_ + c) * HW_;
    float v00 = 0.f, v01 = 0.f, v10 = 0.f, v11 = 0.f;
    bool y0v = (y0 >= 0) && (y0 < H_), y1v = (y0 + 1 >= 0) && (y0 + 1 < H_);
    bool x0v = (x0 >= 0) && (x0 < W_), x1v = (x0 + 1 >= 0) && (x0 + 1 < W_);
    if (y0v && x0v) v00 = b2f(p[y0 * W_ + x0]);
    if (y0v && x1v) v01 = b2f(p[y0 * W_ + x0 + 1]);
    if (y1v && x0v) v10 = b2f(p[(y0 + 1) * W_ + x0]);
    if (y1v && x1v) v11 = b2f(p[(y0 + 1) * W_ + x0 + 1]);

    float v = v00 * (1.f - wx) * (1.f - wy) + v01 * wx * (1.f - wy)
            + v10 * (1.f - wx) * wy + v11 * wx * wy;
    samp[(size_t)(b * C_ + c) * HW_ + hw] = f2b(v);
}

// ---------------------------------------------------------------------------
// Kernel 4: pointwise 1x1 conv 128 -> 256. grid (49, 32, B); 8 oc per thread.
// ---------------------------------------------------------------------------
#define PWT 8
template <typename TI, typename TO>
__device__ void pw_body(const bf16* __restrict__ samp, const TI* __restrict__ pw,
                        TO* __restrict__ out, float* pwl) {
    int tid = threadIdx.x;
    int ocg = blockIdx.y * PWT;
    for (int i = tid; i < C_ * PWT; i += 256) {
        int j = i / C_;
        int c = i - j * C_;
        pwl[c * PWT + j] = rd(pw + (size_t)(ocg + j) * C_ + c);
    }
    __syncthreads();

    int hw = blockIdx.x * 256 + tid;
    int b = blockIdx.z;
    const bf16* sp = samp + (size_t)b * C_ * HW_ + hw;
    float acc[PWT];
#pragma unroll
    for (int j = 0; j < PWT; ++j) acc[j] = 0.f;
    for (int c = 0; c < C_; ++c) {
        float v = b2f(sp[(size_t)c * HW_]);
        const float* wrp = pwl + c * PWT;
#pragma unroll
        for (int j = 0; j < PWT; ++j) acc[j] += v * wrp[j];
    }
    size_t ob = (size_t)b * OUTC_ * HW_ + (size_t)ocg * HW_ + hw;
#pragma unroll
    for (int j = 0; j < PWT; ++j) wr(out + ob + (size_t)j * HW_, acc[j]);
}

__global__ __launch_bounds__(256) void k_pw(const bf16* samp, const void* pw,
                                            void* out, const int* flag) {
    __shared__ float pwl[C_ * PWT];  // 4 KB
    if (*flag) pw_body<float, float>(samp, (const float*)pw, (float*)out, pwl);
    else       pw_body<bf16, bf16>(samp, (const bf16*)pw, (bf16*)out, pwl);
}

// ---------------------------------------------------------------------------
extern "C" void kernel_launch(void* const* d_in, const int* in_sizes, int n_in,
                              void* d_out, int out_size, void* d_ws, size_t ws_size,
                              hipStream_t stream) {
    (void)in_sizes; (void)n_in; (void)out_size; (void)ws_size;
    const void* x        = d_in[0];
    const void* depth_w  = d_in[1];
    const void* point_w  = d_in[2];
    const void* offset_w = d_in[3];
    const void* offset_b = d_in[4];

    char* ws = (char*)d_ws;
    int* flag = (int*)ws;                                  // 256 B slot
    const size_t off_elems = (size_t)B_ * TWOC_ * HW_;     // 51,380,224 fp32
    const size_t dw_elems  = (size_t)B_ * C_ * HW_;        // 25,690,112 bf16
    float* off  = (float*)(ws + 256);
    bf16* dwout = (bf16*)(ws + 256 + off_elems * 4);
    bf16* samp  = (bf16*)(ws + 256 + off_elems * 4 + dw_elems * 2);

    k_probe      <<<1, 256, 0, stream>>>((const unsigned short*)x, flag);
    k_offset_conv<<<dim3(56, B_, TWOC_ / OCT), 256, 0, stream>>>(x, offset_w, offset_b, off, flag);
    k_dw         <<<dim3(49, C_, B_),          256, 0, stream>>>(x, depth_w, dwout, flag);
    k_sample     <<<dim3(49, C_, B_),          256, 0, stream>>>(off, dwout, samp);
    k_pw         <<<dim3(49, OUTC_ / PWT, B_), 256, 0, stream>>>(samp, point_w, d_out, flag);
}

// Round 3
// 2518.341 us; speedup vs baseline: 1.7297x; 1.7297x over previous
//
#include <hip/hip_runtime.h>
#include <hip/hip_bf16.h>

#define B_    16
#define C_    128
#define H_    112
#define W_    112
#define OUTC_ 256
#define TWOC_ 256
#define HW_   (H_ * W_)           // 12544
#define CHW_  ((size_t)C_ * HW_)  // 1605632
#define PH_   114
#define PW_   114
#define PHW_  (PH_ * PW_)         // 12996

typedef __hip_bfloat16 bf16;

__device__ __forceinline__ float b2f(bf16 v) { return __bfloat162float(v); }
__device__ __forceinline__ bf16  f2b(float v) { return __float2bfloat16(v); }

__device__ __forceinline__ float rd(const float* p) { return *p; }
__device__ __forceinline__ float rd(const bf16* p)  { return b2f(*p); }
__device__ __forceinline__ void  wr(float* p, float v) { *p = v; }
__device__ __forceinline__ void  wr(bf16* p,  float v) { *p = f2b(v); }

__device__ __forceinline__ float fast_tanh(float v) {
    float e = __expf(2.f * v);
    return 1.f - 2.f / (e + 1.f);
}

// ---------------------------------------------------------------------------
// Probe: detect input dtype (flag=1 -> fp32, flag=0 -> bf16). See round-1 notes.
// ---------------------------------------------------------------------------
__global__ __launch_bounds__(256) void k_probe(const unsigned short* __restrict__ x,
                                               int* __restrict__ flag) {
    __shared__ int cnt[256];
    int tid = threadIdx.x;
    int c = 0;
#pragma unroll
    for (int i = 0; i < 8; ++i) {
        unsigned short u = x[tid * 8 + i];
        int e = (u >> 7) & 0xFF;
        if (e >= 135) c++;
    }
    cnt[tid] = c;
    __syncthreads();
    if (tid == 0) {
        int s = 0;
        for (int i = 0; i < 256; ++i) s += cnt[i];
        *flag = (s > 64) ? 1 : 0;
    }
}

// ---------------------------------------------------------------------------
// Pad kernel: x (either dtype) -> fp32 padded [B*C, 114, 114], zero halo.
// ---------------------------------------------------------------------------
template <typename TI>
__device__ void pad_body(const TI* __restrict__ x, float* __restrict__ xp) {
    size_t idx = (size_t)blockIdx.x * 256 + threadIdx.x;
    const size_t total = (size_t)B_ * C_ * PHW_;
    if (idx >= total) return;
    int pc  = (int)(idx / PHW_);
    int rem = (int)(idx - (size_t)pc * PHW_);
    int ph = rem / PW_;
    int pw = rem - ph * PW_;
    int h = ph - 1, w = pw - 1;
    float v = 0.f;
    if (h >= 0 && h < H_ && w >= 0 && w < W_)
        v = rd(x + (size_t)pc * HW_ + h * W_ + w);
    xp[idx] = v;
}

__global__ __launch_bounds__(256) void k_pad(const void* x, float* xp, const int* flag) {
    if (*flag) pad_body<float>((const float*)x, xp);
    else       pad_body<bf16>((const bf16*)x, xp);
}

// ---------------------------------------------------------------------------
// Kernel 1: offset = tanh(conv3x3(x, offset_w) + offset_b), fp32 out.
// grid (32 ocg, 28 hblk, 16 b) -- ocg fastest for cross-block L2 reuse of x.
// block 256: wcol = tid&127 (112 active), hq = tid>>7; thread does 2 rows x 8 oc.
// Weights read with wave-uniform indices -> s_load into SGPRs (no LDS at all).
// ---------------------------------------------------------------------------
template <typename TW>
__device__ void conv_body(const float* __restrict__ xp, const TW* __restrict__ ow,
                          const TW* __restrict__ ob, float* __restrict__ off) {
    const int tid  = threadIdx.x;
    const int wcol = tid & 127;
    const int hq   = tid >> 7;
    const int ocb  = blockIdx.x * 8;
    const int hb   = blockIdx.y * 4 + hq * 2;   // output rows hb, hb+1
    const int b    = blockIdx.z;
    if (wcol >= W_) return;   // no barriers below

    // padded addr of (row hb-1 -> padded row hb, col wcol-1 -> padded col wcol)
    const float* xbase = xp + (size_t)b * C_ * PHW_ + (size_t)hb * PW_ + wcol;

    float acc[2][8];
#pragma unroll
    for (int r = 0; r < 2; ++r)
#pragma unroll
        for (int j = 0; j < 8; ++j) acc[r][j] = 0.f;

    for (int c = 0; c < C_; ++c) {
        const float* xc = xbase + (size_t)c * PHW_;
        float xv[4][3];
#pragma unroll
        for (int r = 0; r < 4; ++r)
#pragma unroll
            for (int d = 0; d < 3; ++d)
                xv[r][d] = xc[r * PW_ + d];

        const TW* wc = ow + ((size_t)ocb * C_ + c) * 9;
#pragma unroll
        for (int j = 0; j < 8; ++j) {
            const TW* wj = wc + (size_t)j * C_ * 9;
            float w0 = rd(wj + 0), w1 = rd(wj + 1), w2 = rd(wj + 2);
            float w3 = rd(wj + 3), w4 = rd(wj + 4), w5 = rd(wj + 5);
            float w6 = rd(wj + 6), w7 = rd(wj + 7), w8 = rd(wj + 8);
#pragma unroll
            for (int r = 0; r < 2; ++r) {
                acc[r][j] += xv[r + 0][0] * w0 + xv[r + 0][1] * w1 + xv[r + 0][2] * w2
                           + xv[r + 1][0] * w3 + xv[r + 1][1] * w4 + xv[r + 1][2] * w5
                           + xv[r + 2][0] * w6 + xv[r + 2][1] * w7 + xv[r + 2][2] * w8;
            }
        }
    }

    size_t obase = (size_t)b * TWOC_ * HW_ + (size_t)hb * W_ + wcol;
#pragma unroll
    for (int j = 0; j < 8; ++j) {
        float bias = rd(ob + ocb + j);
#pragma unroll
        for (int r = 0; r < 2; ++r)
            off[obase + (size_t)(ocb + j) * HW_ + r * W_] = fast_tanh(acc[r][j] + bias);
    }
}

__global__ __launch_bounds__(256) void k_offset_conv(
    const float* xp, const void* ow, const void* ob, float* off, const int* flag) {
    if (*flag)
        conv_body<float>(xp, (const float*)ow, (const float*)ob, off);
    else
        conv_body<bf16>(xp, (const bf16*)ow, (const bf16*)ob, off);
}

// ---------------------------------------------------------------------------
// Kernel 2: depthwise 3x3. grid (49, C, B). Reads original x (templated).
// ---------------------------------------------------------------------------
template <typename TI>
__device__ void dw_body(const TI* __restrict__ x, const TI* __restrict__ dw,
                        bf16* __restrict__ out) {
    int hw = blockIdx.x * 256 + threadIdx.x;  // 49*256 == 12544
    int c = blockIdx.y, b = blockIdx.z;
    int h = hw / W_, w = hw - h * W_;
    float wv[9];
#pragma unroll
    for (int k = 0; k < 9; ++k) wv[k] = rd(dw + c * 9 + k);
    const TI* xc = x + (size_t)b * CHW_ + (size_t)c * HW_;
    float acc = 0.f;
#pragma unroll
    for (int kh = 0; kh < 3; ++kh) {
        int hh = h + kh - 1;
        bool hv = (hh >= 0) && (hh < H_);
#pragma unroll
        for (int kw = 0; kw < 3; ++kw) {
            int ww = w + kw - 1;
            bool v = hv && (ww >= 0) && (ww < W_);
            acc += (v ? rd(xc + hh * W_ + ww) : 0.f) * wv[kh * 3 + kw];
        }
    }
    out[(size_t)(b * C_ + c) * HW_ + hw] = f2b(acc);
}

__global__ __launch_bounds__(256) void k_dw(const void* x, const void* dw,
                                            bf16* out, const int* flag) {
    if (*flag) dw_body<float>((const float*)x, (const float*)dw, out);
    else       dw_body<bf16>((const bf16*)x, (const bf16*)dw, out);
}

// ---------------------------------------------------------------------------
// Kernel 3: grid sample. Channel c uses offset channels (2c, 2c+1); BOTH
// coordinate bases are gX[w] for c<64 and gY[h] for c>=64 (ref reshape quirk).
// ---------------------------------------------------------------------------
__global__ __launch_bounds__(256) void k_sample(
    const float* __restrict__ off, const bf16* __restrict__ dwout,
    bf16* __restrict__ samp) {
    int hw = blockIdx.x * 256 + threadIdx.x;
    int c = blockIdx.y, b = blockIdx.z;
    int h = hw / W_, w = hw - h * W_;

    float gbase = (c < 64) ? (-1.f + 2.f * (float)w / 111.f)
                           : (-1.f + 2.f * (float)h / 111.f);
    const float* offb = off + (size_t)b * TWOC_ * HW_;
    float ox = offb[(size_t)(2 * c) * HW_ + hw];
    float oy = offb[(size_t)(2 * c + 1) * HW_ + hw];
    float gx = fminf(fmaxf(gbase + ox, -1.f), 1.f);
    float gy = fminf(fmaxf(gbase + oy, -1.f), 1.f);
    float ix = (gx + 1.f) * 56.f - 0.5f;
    float iy = (gy + 1.f) * 56.f - 0.5f;
    float x0f = floorf(ix), y0f = floorf(iy);
    float wx = ix - x0f, wy = iy - y0f;
    int x0 = (int)x0f, y0 = (int)y0f;

    const bf16* p = dwout + (size_t)(b * C_ + c) * HW_;
    float v00 = 0.f, v01 = 0.f, v10 = 0.f, v11 = 0.f;
    bool y0v = (y0 >= 0) && (y0 < H_), y1v = (y0 + 1 >= 0) && (y0 + 1 < H_);
    bool x0v = (x0 >= 0) && (x0 < W_), x1v = (x0 + 1 >= 0) && (x0 + 1 < W_);
    if (y0v && x0v) v00 = b2f(p[y0 * W_ + x0]);
    if (y0v && x1v) v01 = b2f(p[y0 * W_ + x0 + 1]);
    if (y1v && x0v) v10 = b2f(p[(y0 + 1) * W_ + x0]);
    if (y1v && x1v) v11 = b2f(p[(y0 + 1) * W_ + x0 + 1]);

    float v = v00 * (1.f - wx) * (1.f - wy) + v01 * wx * (1.f - wy)
            + v10 * (1.f - wx) * wy + v11 * wx * wy;
    samp[(size_t)(b * C_ + c) * HW_ + hw] = f2b(v);
}

// ---------------------------------------------------------------------------
// Kernel 4: pointwise 1x1 conv 128 -> 256. grid (49, 32, B); 8 oc per thread.
// ---------------------------------------------------------------------------
#define PWT 8
template <typename TI, typename TO>
__device__ void pw_body(const bf16* __restrict__ samp, const TI* __restrict__ pw,
                        TO* __restrict__ out, float* pwl) {
    int tid = threadIdx.x;
    int ocg = blockIdx.y * PWT;
    for (int i = tid; i < C_ * PWT; i += 256) {
        int j = i / C_;
        int c = i - j * C_;
        pwl[c * PWT + j] = rd(pw + (size_t)(ocg + j) * C_ + c);
    }
    __syncthreads();

    int hw = blockIdx.x * 256 + tid;
    int b = blockIdx.z;
    const bf16* sp = samp + (size_t)b * C_ * HW_ + hw;
    float acc[PWT];
#pragma unroll
    for (int j = 0; j < PWT; ++j) acc[j] = 0.f;
    for (int c = 0; c < C_; ++c) {
        float v = b2f(sp[(size_t)c * HW_]);
        const float* wrp = pwl + c * PWT;
#pragma unroll
        for (int j = 0; j < PWT; ++j) acc[j] += v * wrp[j];
    }
    size_t ob = (size_t)b * OUTC_ * HW_ + (size_t)ocg * HW_ + hw;
#pragma unroll
    for (int j = 0; j < PWT; ++j) wr(out + ob + (size_t)j * HW_, acc[j]);
}

__global__ __launch_bounds__(256) void k_pw(const bf16* samp, const void* pw,
                                            void* out, const int* flag) {
    __shared__ float pwl[C_ * PWT];  // 4 KB
    if (*flag) pw_body<float, float>(samp, (const float*)pw, (float*)out, pwl);
    else       pw_body<bf16, bf16>(samp, (const bf16*)pw, (bf16*)out, pwl);
}

// ---------------------------------------------------------------------------
// Workspace layout (312 MB total; padbuf is reused for dwout+samp after conv):
//   [0,256)                      : dtype flag
//   [256, 256+106463232)         : padbuf fp32 (B*C*114*114)
//        after conv: dwout bf16 (51380224 B) at padbuf+0,
//                    samp  bf16 (51380224 B) at padbuf+51380224
//   [256+106463232, +205520896)  : off fp32 (B*2C*HW)
// ---------------------------------------------------------------------------
extern "C" void kernel_launch(void* const* d_in, const int* in_sizes, int n_in,
                              void* d_out, int out_size, void* d_ws, size_t ws_size,
                              hipStream_t stream) {
    (void)in_sizes; (void)n_in; (void)out_size; (void)ws_size;
    const void* x        = d_in[0];
    const void* depth_w  = d_in[1];
    const void* point_w  = d_in[2];
    const void* offset_w = d_in[3];
    const void* offset_b = d_in[4];

    char* ws = (char*)d_ws;
    int*   flag = (int*)ws;
    float* xp   = (float*)(ws + 256);
    const size_t pad_bytes = (size_t)B_ * C_ * PHW_ * 4;  // 106,463,232
    float* off  = (float*)(ws + 256 + pad_bytes);
    bf16* dwout = (bf16*)(ws + 256);                       // reuse padbuf
    bf16* samp  = (bf16*)(ws + 256 + (size_t)B_ * C_ * HW_ * 2);

    const int pad_blocks = (int)(((size_t)B_ * C_ * PHW_ + 255) / 256);  // 103969

    k_probe      <<<1, 256, 0, stream>>>((const unsigned short*)x, flag);
    k_pad        <<<pad_blocks, 256, 0, stream>>>(x, xp, flag);
    k_offset_conv<<<dim3(TWOC_ / 8, H_ / 4, B_), 256, 0, stream>>>(xp, offset_w, offset_b, off, flag);
    k_dw         <<<dim3(49, C_, B_),          256, 0, stream>>>(x, depth_w, dwout, flag);
    k_sample     <<<dim3(49, C_, B_),          256, 0, stream>>>(off, dwout, samp);
    k_pw         <<<dim3(49, OUTC_ / PWT, B_), 256, 0, stream>>>(samp, point_w, d_out, flag);
}